// Round 13
// baseline (42.867 us; speedup 1.0000x reference)
//
#include <hip/hip_runtime.h>

// SIMcLoss: x [8192, 256] fp32 -> scalar.
// loss = (||Xn^T Xn||_F^2 - n)/(n^2 - n) on the 256x256 Gram matrix.
// TWO dispatches:
//   k_gram_all : 256 blocks x 512 thr; block owns 32 rows and computes ALL
//                10 upper tile-pairs for them. Staging pass reads each row
//                ONCE (full row -> norm via shuffle -> bf16 RNE -> LDS
//                transposed+swizzled). One barrier. 20 MFMA/wave with
//                4-way A-frag reuse. fp32 partial slab (160 KB) per block.
//                No k_prep, no redundant reads, no cross-block sync.
//   k_reduce   : 640 blocks; per-element sum of 256 chunk partials,
//                weight, square, block reduce, atomicAdd(S), ticket -> loss.
#define D 256
#define TILE 64
#define NBLK 256          // 32-row chunks
#define EPS 1e-8f

typedef __attribute__((ext_vector_type(8))) short bf16x8;
typedef __attribute__((ext_vector_type(4))) float f32x4;

__device__ __forceinline__ void pair_decode(int p, int& ta, int& tb) {
  if (p < 4)      { ta = 0; tb = p; }
  else if (p < 7) { ta = 1; tb = p - 3; }
  else if (p < 9) { ta = 2; tb = p - 5; }
  else            { ta = 3; tb = 3; }
}

// swizzled short-index into X[col][64-row sparse] (row-stride 64 shorts).
// XOR bits 3..5 of row with g(col): b128 frag reads ~2-way conflicts.
__device__ __forceinline__ int swz(int col, int r) {
  int g = ((col >> 2) & 7) ^ ((col & 3) << 1);
  return col * 64 + (r ^ (g << 3));
}

// round-to-nearest-even fp32 -> bf16 (truncation would bias S)
__device__ __forceinline__ unsigned short rne_bf16(float f) {
  unsigned u = __float_as_uint(f);
  return (unsigned short)((u + 0x7fffu + ((u >> 16) & 1u)) >> 16);
}

// ---------------------------------------------------------------------------
// Kernel 1: fused norms + all-pairs Gram. 256 blocks x 512 threads.
// ---------------------------------------------------------------------------
__global__ __launch_bounds__(512) void k_gram_all(
    const float* __restrict__ x, float* __restrict__ slabs,
    float* __restrict__ ctrl) {
  const int bid = blockIdx.x;
  const int tid = threadIdx.x;
  const int w = tid >> 6, lane = tid & 63;
  if (bid == 0 && tid < 16) ctrl[tid] = 0.0f;   // S, cnt (reduce runs later)

  __shared__ short X[256 * 64];                 // 32 KB, [col][row^swz]
  const int row0 = bid * 32;

  // ---- staging: wave w -> rows w*4 .. w*4+3 (read once, norm, convert) ----
  {
    const int r0w = w * 4;
    float4 v[4];
    #pragma unroll
    for (int j = 0; j < 4; ++j)
      v[j] = reinterpret_cast<const float4*>(
          x + (size_t)(row0 + r0w + j) * D)[lane];
    unsigned short hh[4][4];
    #pragma unroll
    for (int j = 0; j < 4; ++j) {
      float s = v[j].x * v[j].x + v[j].y * v[j].y +
                v[j].z * v[j].z + v[j].w * v[j].w;
      #pragma unroll
      for (int o = 32; o > 0; o >>= 1) s += __shfl_xor(s, o);
      const float iv = 1.0f / fmaxf(sqrtf(s), EPS);
      hh[j][0] = rne_bf16(v[j].x * iv);
      hh[j][1] = rne_bf16(v[j].y * iv);
      hh[j][2] = rne_bf16(v[j].z * iv);
      hh[j][3] = rne_bf16(v[j].w * iv);
    }
    #pragma unroll
    for (int cc = 0; cc < 4; ++cc)
      *reinterpret_cast<ushort4*>(&X[swz(lane * 4 + cc, r0w)]) =
          make_ushort4(hh[0][cc], hh[1][cc], hh[2][cc], hh[3][cc]);
  }
  __syncthreads();

  // ---- MFMA: wave w owns (p,qi) combos 5w..5w+4; 4 qj each; K=32 ----
  const int lm = lane & 15, lk = lane >> 4;
  f32x4 zero = {0.f, 0.f, 0.f, 0.f};
  f32x4 acc[5][4];
  #pragma unroll
  for (int a = 0; a < 5; ++a)
    #pragma unroll
    for (int b = 0; b < 4; ++b) acc[a][b] = zero;

  #pragma unroll
  for (int k0 = 0; k0 < 5; ++k0) {
    const int k = w * 5 + k0;
    const int p = k >> 2, qi = k & 3;
    int ta, tb; pair_decode(p, ta, tb);
    const bf16x8 A = *reinterpret_cast<const bf16x8*>(
        &X[swz(ta * TILE + qi * 16 + lm, lk * 8)]);
    #pragma unroll
    for (int qj = 0; qj < 4; ++qj) {
      const bf16x8 B = *reinterpret_cast<const bf16x8*>(
          &X[swz(tb * TILE + qj * 16 + lm, lk * 8)]);
      acc[k0][qj] = __builtin_amdgcn_mfma_f32_16x16x32_bf16(
          A, B, acc[k0][qj], 0, 0, 0);
    }
  }

  // ---- epilogue: C/D layout col=lane&15, row=(lane>>4)*4+reg (m89) ----
  float* slab = slabs + (size_t)bid * (10 * TILE * TILE);
  #pragma unroll
  for (int k0 = 0; k0 < 5; ++k0) {
    const int k = w * 5 + k0;
    const int p = k >> 2, qi = k & 3;
    float* tbase = slab + p * 4096 + (qi * 16 + lk * 4) * TILE + lm;
    #pragma unroll
    for (int qj = 0; qj < 4; ++qj)
      #pragma unroll
      for (int rg = 0; rg < 4; ++rg)
        tbase[rg * TILE + qj * 16] = acc[k0][qj][rg];
  }
}

// ---------------------------------------------------------------------------
// Kernel 2: reduce. 640 blocks x 256 threads. Block b: pair p=b>>6,
// elements e0..e0+63. Thread (el, cg): sums 64 chunks; LDS-combine 4 groups,
// weight, square, wave-reduce, atomicAdd(S), last-block ticket -> loss.
// ---------------------------------------------------------------------------
__global__ __launch_bounds__(256) void k_reduce(
    const float* __restrict__ slabs, float* __restrict__ S,
    unsigned int* __restrict__ cnt, float* __restrict__ out,
    int N, int nblocks) {
  const int b = blockIdx.x;
  const int p = b >> 6;                         // pair 0..9
  const int e0 = (b & 63) << 6;                 // element group
  const int el = threadIdx.x & 63;
  const int cg = threadIdx.x >> 6;              // chunk group 0..3

  const float* base = slabs + (size_t)p * 4096 + e0 + el;
  const size_t step = (size_t)10 * TILE * TILE; // 40960 floats per chunk
  float t = 0.f;
  #pragma unroll 8
  for (int i = 0; i < 64; ++i)
    t += base[(size_t)(cg * 64 + i) * step];

  __shared__ float sm[4][64];
  sm[cg][el] = t;
  __syncthreads();

  if (threadIdx.x < 64) {
    const float tot = sm[0][el] + sm[1][el] + sm[2][el] + sm[3][el];
    const bool diag = (p == 0) | (p == 4) | (p == 7) | (p == 9);
    float part = (diag ? 1.f : 2.f) * tot * tot;
    #pragma unroll
    for (int o = 32; o > 0; o >>= 1) part += __shfl_xor(part, o);
    if (threadIdx.x == 0) {
      atomicAdd(S, part);
      __threadfence();
      unsigned int old = atomicAdd(cnt, 1u);
      if (old == (unsigned int)(nblocks - 1)) {
        float Sv = __hip_atomic_load(S, __ATOMIC_RELAXED,
                                     __HIP_MEMORY_SCOPE_AGENT);
        float nf = (float)N;
        out[0] = (Sv - nf) / (nf * nf - nf);
      }
    }
  }
}

extern "C" void kernel_launch(void* const* d_in, const int* in_sizes, int n_in,
                              void* d_out, int out_size, void* d_ws, size_t ws_size,
                              hipStream_t stream) {
  const float* x = (const float*)d_in[0];
  float* out = (float*)d_out;
  const int N = in_sizes[0] / D;       // 8192

  // ws layout (floats): ctrl[64] (S, cnt) | slabs[256 * 40960]
  float* ctrl = (float*)d_ws;
  float* S = ctrl;
  unsigned int* cnt = (unsigned int*)(ctrl + 1);
  float* slabs = ctrl + 64;

  k_gram_all<<<dim3(NBLK), dim3(512), 0, stream>>>(x, slabs, ctrl);
  const int nb = 640;
  k_reduce<<<dim3(nb), dim3(256), 0, stream>>>(slabs, S, cnt, out, N, nb);
}

// Round 15
// 29.839 us; speedup vs baseline: 1.4366x; 1.4366x over previous
//
#include <hip/hip_runtime.h>

// SIMcLoss: x [8192, 256] fp32 -> scalar.
// loss = (||Xn^T Xn||_F^2 - n)/(n^2 - n) on the 256x256 Gram matrix.
// TWO dispatches, minimal total traffic:
//   k_gram_all : 64 blocks x 512 thr; block owns 128 rows (2 sub-chunks of
//                64), computes ALL 10 upper tile-pairs. Staging reads each
//                row ONCE; row norm comes from the staging loads via wave
//                butterfly (wave w's 64 lanes hold all 64 col-groups of
//                rows 4w..4w+3). bf16 RNE -> LDS [256 col][64 row] swizzled
//                (R5-proven geometry). 80 MFMA/wave. Slab 160 KB/block
//                (10 MB total -- R13's 40 MB was the regression cause).
//   k_reduce   : 160 blocks; thread-per-G-element, 64 coalesced partials,
//                weight, square, block reduce, atomicAdd(S), ticket -> loss.
#define D 256
#define TILE 64
#define NBLK 64           // 128-row chunks
#define EPS 1e-8f

typedef __attribute__((ext_vector_type(8))) short bf16x8;
typedef __attribute__((ext_vector_type(4))) float f32x4;

__device__ __forceinline__ void pair_decode(int p, int& ta, int& tb) {
  if (p < 4)      { ta = 0; tb = p; }
  else if (p < 7) { ta = 1; tb = p - 3; }
  else if (p < 9) { ta = 2; tb = p - 5; }
  else            { ta = 3; tb = 3; }
}

// swizzled short-index into X[col][64 rows] (row-stride 64 shorts = 128 B).
// XOR bits 3..5 of row with g(col): b128 frag reads ~2-way, b64 writes ~4-way.
__device__ __forceinline__ int swz(int col, int r) {
  int g = ((col >> 2) & 7) ^ ((col & 3) << 1);
  return col * 64 + (r ^ (g << 3));
}

// round-to-nearest-even fp32 -> bf16 (truncation would bias S)
__device__ __forceinline__ unsigned short rne_bf16(float f) {
  unsigned u = __float_as_uint(f);
  return (unsigned short)((u + 0x7fffu + ((u >> 16) & 1u)) >> 16);
}

// ---------------------------------------------------------------------------
// Kernel 1: fused norms + all-pairs Gram. 64 blocks x 512 threads.
// ---------------------------------------------------------------------------
__global__ __launch_bounds__(512) void k_gram_all(
    const float* __restrict__ x, float* __restrict__ slabs,
    float* __restrict__ ctrl) {
  const int bid = blockIdx.x;
  const int tid = threadIdx.x;
  const int w = tid >> 6, lane = tid & 63;
  if (bid == 0 && tid < 16) ctrl[tid] = 0.0f;   // S, cnt (reduce is next node)

  __shared__ short X[256 * 64];                 // 32 KB, [col][row^swz]
  const int row0 = bid * 128;

  // task t (2 per thread): rows (t>>6)*4 .. +3, cols (t&63)*4 .. +3.
  // For thread tid, task0 = tid -> row-block w (lanes = 64 col-groups!),
  // task1 = tid+512 -> row-block w+8.
  const int lm = lane & 15, lk = lane >> 4;

  f32x4 zero = {0.f, 0.f, 0.f, 0.f};
  f32x4 acc[5][4];
  #pragma unroll
  for (int a = 0; a < 5; ++a)
    #pragma unroll
    for (int b = 0; b < 4; ++b) acc[a][b] = zero;

  // prefetch sub-chunk 0 (both tasks: 8 float4)
  float4 pv[2][4];
  #pragma unroll
  for (int t = 0; t < 2; ++t) {
    const int r0 = (w + t * 8) * 4;
    #pragma unroll
    for (int j = 0; j < 4; ++j)
      pv[t][j] = reinterpret_cast<const float4*>(
          x + (size_t)(row0 + r0 + j) * D)[lane];
  }

  #pragma unroll
  for (int sub = 0; sub < 2; ++sub) {
    // ---- stage: norm via butterfly on staging values, convert, write ----
    #pragma unroll
    for (int t = 0; t < 2; ++t) {
      const int r0 = (w + t * 8) * 4;           // row base in sub-chunk
      const int c0 = lane * 4;                  // col base
      unsigned short hh[4][4];
      #pragma unroll
      for (int j = 0; j < 4; ++j) {
        const float4 v = pv[t][j];
        float s = v.x * v.x + v.y * v.y + v.z * v.z + v.w * v.w;
        #pragma unroll
        for (int o = 32; o > 0; o >>= 1) s += __shfl_xor(s, o);
        const float iv = 1.0f / fmaxf(sqrtf(s), EPS);
        hh[j][0] = rne_bf16(v.x * iv);
        hh[j][1] = rne_bf16(v.y * iv);
        hh[j][2] = rne_bf16(v.z * iv);
        hh[j][3] = rne_bf16(v.w * iv);
      }
      #pragma unroll
      for (int cc = 0; cc < 4; ++cc)
        *reinterpret_cast<ushort4*>(&X[swz(c0 + cc, r0)]) =
            make_ushort4(hh[0][cc], hh[1][cc], hh[2][cc], hh[3][cc]);
    }
    // issue next sub-chunk's loads (hide HBM latency under MFMA phase)
    if (sub == 0) {
      #pragma unroll
      for (int t = 0; t < 2; ++t) {
        const int r0 = (w + t * 8) * 4;
        #pragma unroll
        for (int j = 0; j < 4; ++j)
          pv[t][j] = reinterpret_cast<const float4*>(
              x + (size_t)(row0 + 64 + r0 + j) * D)[lane];
      }
    }
    __syncthreads();

    // ---- MFMA: wave w owns (p,qi) combos 5w..5w+4; 4 qj; 2 K-steps ----
    #pragma unroll
    for (int rr = 0; rr < 64; rr += 32) {
      const int rbase = rr + lk * 8;
      #pragma unroll
      for (int k0 = 0; k0 < 5; ++k0) {
        const int k = w * 5 + k0;
        const int p = k >> 2, qi = k & 3;
        int ta, tb; pair_decode(p, ta, tb);
        const bf16x8 A = *reinterpret_cast<const bf16x8*>(
            &X[swz(ta * TILE + qi * 16 + lm, rbase)]);
        #pragma unroll
        for (int qj = 0; qj < 4; ++qj) {
          const bf16x8 B = *reinterpret_cast<const bf16x8*>(
              &X[swz(tb * TILE + qj * 16 + lm, rbase)]);
          acc[k0][qj] = __builtin_amdgcn_mfma_f32_16x16x32_bf16(
              A, B, acc[k0][qj], 0, 0, 0);
        }
      }
    }
    if (sub == 0) __syncthreads();              // before re-staging
  }

  // ---- epilogue: C/D layout col=lane&15, row=(lane>>4)*4+reg (m89) ----
  float* slab = slabs + (size_t)bid * (10 * TILE * TILE);
  #pragma unroll
  for (int k0 = 0; k0 < 5; ++k0) {
    const int k = w * 5 + k0;
    const int p = k >> 2, qi = k & 3;
    float* tbase = slab + p * 4096 + (qi * 16 + lk * 4) * TILE + lm;
    #pragma unroll
    for (int qj = 0; qj < 4; ++qj)
      #pragma unroll
      for (int rg = 0; rg < 4; ++rg)
        tbase[rg * TILE + qj * 16] = acc[k0][qj][rg];
  }
}

// ---------------------------------------------------------------------------
// Kernel 2: reduce. 160 blocks x 256 threads; one G element per thread:
// sum 64 chunk partials (coalesced, stride 160 KB), weight, square,
// block-reduce, atomicAdd(S), last-block ticket -> loss.
// ---------------------------------------------------------------------------
__global__ __launch_bounds__(256) void k_reduce(
    const float* __restrict__ slabs, float* __restrict__ S,
    unsigned int* __restrict__ cnt, float* __restrict__ out,
    int N, int nblocks) {
  const int g = blockIdx.x * 256 + threadIdx.x;
  const int p = g >> 12;                        // pair 0..9
  const int e = g & 4095;                       // element in 64x64 tile
  const float* base = slabs + (size_t)p * 4096 + e;
  const size_t step = (size_t)10 * TILE * TILE; // 40960 floats per chunk
  float t0 = 0.f, t1 = 0.f, t2 = 0.f, t3 = 0.f;
  #pragma unroll 4
  for (int c = 0; c < NBLK; c += 4) {
    t0 += base[(size_t)(c + 0) * step];
    t1 += base[(size_t)(c + 1) * step];
    t2 += base[(size_t)(c + 2) * step];
    t3 += base[(size_t)(c + 3) * step];
  }
  const float tot = (t0 + t1) + (t2 + t3);
  const bool diag = (p == 0) | (p == 4) | (p == 7) | (p == 9);
  float part = (diag ? 1.f : 2.f) * tot * tot;
  #pragma unroll
  for (int o = 32; o > 0; o >>= 1) part += __shfl_xor(part, o);
  __shared__ float red[4];
  int lane = threadIdx.x & 63, w = threadIdx.x >> 6;
  if (lane == 0) red[w] = part;
  __syncthreads();
  if (threadIdx.x == 0) {
    float blk = red[0] + red[1] + red[2] + red[3];
    atomicAdd(S, blk);
    __threadfence();
    unsigned int old = atomicAdd(cnt, 1u);
    if (old == (unsigned int)(nblocks - 1)) {
      float Sv = __hip_atomic_load(S, __ATOMIC_RELAXED,
                                   __HIP_MEMORY_SCOPE_AGENT);
      float nf = (float)N;
      out[0] = (Sv - nf) / (nf * nf - nf);
    }
  }
}

extern "C" void kernel_launch(void* const* d_in, const int* in_sizes, int n_in,
                              void* d_out, int out_size, void* d_ws, size_t ws_size,
                              hipStream_t stream) {
  const float* x = (const float*)d_in[0];
  float* out = (float*)d_out;
  const int N = in_sizes[0] / D;       // 8192

  // ws layout (floats): ctrl[64] (S, cnt) | slabs[64 * 40960]
  float* ctrl = (float*)d_ws;
  float* S = ctrl;
  unsigned int* cnt = (unsigned int*)(ctrl + 1);
  float* slabs = ctrl + 64;

  k_gram_all<<<dim3(NBLK), dim3(512), 0, stream>>>(x, slabs, ctrl);
  const int nb = 160;
  k_reduce<<<dim3(nb), dim3(256), 0, stream>>>(slabs, S, cnt, out, N, nb);
}